// Round 1
// baseline (103.521 us; speedup 1.0000x reference)
//
#include <hip/hip_runtime.h>
#include <hip/hip_bf16.h>

// Problem constants (B=4, L=4096, C=512, H=16, Dh=32, K=13)
#define BATCH   4
#define LSEQ    4096
#define CCH     512
#define HNUM    16
#define DH      32
#define KSZ     13
#define NHALF   6           // K/2
#define M_TOT   16384       // B*L
#define N_QKV   1536        // 3*C
#define KDIM    512         // C

typedef __attribute__((ext_vector_type(8))) short  short8;
typedef __attribute__((ext_vector_type(4))) short  short4_t;
typedef __attribute__((ext_vector_type(4))) float  float4_t;

__device__ __forceinline__ unsigned short f32_to_bf16(float f) {
    union { float f; unsigned int u; } un; un.f = f;
    unsigned int u = un.u;
    u += 0x7FFFu + ((u >> 16) & 1u);   // RNE (inputs are finite)
    return (unsigned short)(u >> 16);
}
__device__ __forceinline__ float bf16_to_f32(unsigned short h) {
    union { unsigned int u; float f; } un; un.u = ((unsigned int)h) << 16;
    return un.f;
}

// ---------------------------------------------------------------- cvt weights
__global__ void cvt_f32_bf16_v4(const float4_t* __restrict__ in,
                                short4_t* __restrict__ out, int n4) {
    int i = blockIdx.x * blockDim.x + threadIdx.x;
    if (i < n4) {
        float4_t v = in[i];
        short4_t h;
        h.x = (short)f32_to_bf16(v.x);
        h.y = (short)f32_to_bf16(v.y);
        h.z = (short)f32_to_bf16(v.z);
        h.w = (short)f32_to_bf16(v.w);
        out[i] = h;
    }
}

// ---------------------------------------------------------------- GEMM 1: QKV
// X (f32, 16384x512) @ W^T (W bf16 1536x512) + bias -> qkv bf16 (3,B,H,L,Dh)
// 128x128 tile, BK=32, 4 waves each computing 64x64 (4x4 of 16x16x32 MFMA).
#define LDSP 40   // 32 + 8 pad (row stride 80B: 16B-aligned, 2-way conflicts max)

__global__ __launch_bounds__(256) void gemm_qkv(
    const float* __restrict__ X,
    const unsigned short* __restrict__ W,
    const float* __restrict__ bias,
    unsigned short* __restrict__ qkvout)
{
    __shared__ unsigned short As[128 * LDSP];
    __shared__ unsigned short Bs[128 * LDSP];
    const int tid  = threadIdx.x;
    const int m0   = blockIdx.x * 128;
    const int n0   = blockIdx.y * 128;
    const int wave = tid >> 6, lane = tid & 63;
    const int wm   = (wave >> 1) * 64;
    const int wn   = (wave & 1) * 64;
    const int lr   = lane & 15;        // fragment row/col
    const int lg   = lane >> 4;        // k-group (0..3)

    float4_t acc[4][4];
    #pragma unroll
    for (int m = 0; m < 4; ++m)
        #pragma unroll
        for (int n = 0; n < 4; ++n)
            acc[m][n] = (float4_t){0.f, 0.f, 0.f, 0.f};

    for (int k0 = 0; k0 < KDIM; k0 += 32) {
        // stage A: 128 rows x 32 f32 -> bf16 (convert on the fly)
        #pragma unroll
        for (int it = 0; it < 4; ++it) {
            int slot = it * 256 + tid;         // 1024 slots
            int row = slot >> 3, cq = slot & 7;
            float4_t xv = *reinterpret_cast<const float4_t*>(
                X + (size_t)(m0 + row) * KDIM + k0 + cq * 4);
            short4_t h;
            h.x = (short)f32_to_bf16(xv.x);
            h.y = (short)f32_to_bf16(xv.y);
            h.z = (short)f32_to_bf16(xv.z);
            h.w = (short)f32_to_bf16(xv.w);
            *reinterpret_cast<short4_t*>(&As[row * LDSP + cq * 4]) = h;
        }
        // stage B: 128 rows x 32 bf16
        #pragma unroll
        for (int it = 0; it < 2; ++it) {
            int slot = it * 256 + tid;         // 512 slots
            int row = slot >> 2, cq = slot & 3;
            *reinterpret_cast<short8*>(&Bs[row * LDSP + cq * 8]) =
                *reinterpret_cast<const short8*>(
                    W + (size_t)(n0 + row) * KDIM + k0 + cq * 8);
        }
        __syncthreads();
        short8 af[4], bfr[4];
        #pragma unroll
        for (int m = 0; m < 4; ++m)
            af[m] = *reinterpret_cast<const short8*>(
                &As[(wm + m * 16 + lr) * LDSP + lg * 8]);
        #pragma unroll
        for (int n = 0; n < 4; ++n)
            bfr[n] = *reinterpret_cast<const short8*>(
                &Bs[(wn + n * 16 + lr) * LDSP + lg * 8]);
        #pragma unroll
        for (int m = 0; m < 4; ++m)
            #pragma unroll
            for (int n = 0; n < 4; ++n)
                acc[m][n] = __builtin_amdgcn_mfma_f32_16x16x32_bf16(
                    af[m], bfr[n], acc[m][n], 0, 0, 0);
        __syncthreads();
    }

    // epilogue: bias, q-scale, scatter to (3,B,H,L,Dh) bf16
    const float qscale = 0.17677669529663687f;  // Dh^-0.5
    #pragma unroll
    for (int m = 0; m < 4; ++m) {
        #pragma unroll
        for (int n = 0; n < 4; ++n) {
            int gn    = n0 + wn + n * 16 + lr;
            int which = gn >> 9;            // 0=q 1=k 2=v
            int hh    = (gn >> 5) & 15;
            int dd    = gn & 31;
            float bsv = bias[gn];
            #pragma unroll
            for (int r = 0; r < 4; ++r) {
                int gm = m0 + wm + m * 16 + lg * 4 + r;
                float v = acc[m][n][r] + bsv;
                if (which == 0) v *= qscale;
                int b_ = gm >> 12, l = gm & 4095;
                size_t off = (((size_t)which * BATCH + b_) * HNUM + hh) *
                                 ((size_t)LSEQ * DH) + (size_t)l * DH + dd;
                qkvout[off] = f32_to_bf16(v);
            }
        }
    }
}

// ---------------------------------------------------------------- attention
// one block = (b, h, 256 consecutive l). K/V window staged in LDS.
__global__ __launch_bounds__(256) void natten_fwd(
    const unsigned short* __restrict__ qkv,  // (3,B,H,L,Dh) bf16
    const float* __restrict__ rpb,           // (16,25) f32
    unsigned short* __restrict__ ctx)        // (B,L,C) bf16
{
    __shared__ unsigned short ks[268 * DH];
    __shared__ unsigned short vs[268 * DH];
    __shared__ float rpb_s[2 * KSZ - 1];

    const int t    = threadIdx.x;
    const int lblk = blockIdx.x & 15;       // L/256 = 16 chunks
    const int bh   = blockIdx.x >> 4;
    const int hh   = bh & 15, b_ = bh >> 4;
    const int l0   = lblk * 256;

    const int r0    = max(l0 - NHALF, 0);
    const int rend  = min(l0 + 256 + NHALF, LSEQ);
    const int nrows = rend - r0;            // <= 268

    const size_t plane = (size_t)LSEQ * DH;
    const size_t kbase = (((size_t)1 * BATCH + b_) * HNUM + hh) * plane;
    const size_t vbase = (((size_t)2 * BATCH + b_) * HNUM + hh) * plane;

    for (int slot = t; slot < nrows * 4; slot += 256) {
        int row = slot >> 2, cq = slot & 3;
        *reinterpret_cast<short8*>(&ks[row * DH + cq * 8]) =
            *reinterpret_cast<const short8*>(&qkv[kbase + (size_t)(r0 + row) * DH + cq * 8]);
        *reinterpret_cast<short8*>(&vs[row * DH + cq * 8]) =
            *reinterpret_cast<const short8*>(&qkv[vbase + (size_t)(r0 + row) * DH + cq * 8]);
    }
    if (t < 2 * KSZ - 1) rpb_s[t] = rpb[hh * (2 * KSZ - 1) + t];
    __syncthreads();

    const int l = l0 + t;
    float q[DH];
    const size_t qoff = (((size_t)0 * BATCH + b_) * HNUM + hh) * plane + (size_t)l * DH;
    #pragma unroll
    for (int cq = 0; cq < 4; ++cq) {
        short8 qv = *reinterpret_cast<const short8*>(&qkv[qoff + cq * 8]);
        #pragma unroll
        for (int e = 0; e < 8; ++e) q[cq * 8 + e] = bf16_to_f32((unsigned short)qv[e]);
    }

    const int start = min(max(l - NHALF, 0), LSEQ - KSZ);
    float logit[KSZ];
    #pragma unroll
    for (int j = 0; j < KSZ; ++j) {
        int kr = start + j - r0;
        float s = 0.f;
        #pragma unroll
        for (int cq = 0; cq < 4; ++cq) {
            short8 kv = *reinterpret_cast<const short8*>(&ks[kr * DH + cq * 8]);
            #pragma unroll
            for (int e = 0; e < 8; ++e)
                s += q[cq * 8 + e] * bf16_to_f32((unsigned short)kv[e]);
        }
        logit[j] = s + rpb_s[start + j - l + (KSZ - 1)];
    }
    float mx = logit[0];
    #pragma unroll
    for (int j = 1; j < KSZ; ++j) mx = fmaxf(mx, logit[j]);
    float p[KSZ], sum = 0.f;
    #pragma unroll
    for (int j = 0; j < KSZ; ++j) { p[j] = __expf(logit[j] - mx); sum += p[j]; }
    const float inv = 1.f / sum;

    float o[DH];
    #pragma unroll
    for (int d = 0; d < DH; ++d) o[d] = 0.f;
    #pragma unroll
    for (int j = 0; j < KSZ; ++j) {
        int kr = start + j - r0;
        float pj = p[j] * inv;
        #pragma unroll
        for (int cq = 0; cq < 4; ++cq) {
            short8 vv = *reinterpret_cast<const short8*>(&vs[kr * DH + cq * 8]);
            #pragma unroll
            for (int e = 0; e < 8; ++e)
                o[cq * 8 + e] += pj * bf16_to_f32((unsigned short)vv[e]);
        }
    }
    const size_t obase = ((size_t)(b_ * LSEQ + l)) * CCH + hh * DH;
    #pragma unroll
    for (int cq = 0; cq < 4; ++cq) {
        short8 ov;
        #pragma unroll
        for (int e = 0; e < 8; ++e) ov[e] = (short)f32_to_bf16(o[cq * 8 + e]);
        *reinterpret_cast<short8*>(&ctx[obase + cq * 8]) = ov;
    }
}

// ---------------------------------------------------------------- GEMM 2: proj
// ctx (bf16, 16384x512) @ W^T (W bf16 512x512) + bias -> out f32 (B,L,C)
__global__ __launch_bounds__(256) void gemm_proj(
    const unsigned short* __restrict__ Xb,
    const unsigned short* __restrict__ W,
    const float* __restrict__ bias,
    float* __restrict__ out)
{
    __shared__ unsigned short As[128 * LDSP];
    __shared__ unsigned short Bs[128 * LDSP];
    const int tid  = threadIdx.x;
    const int m0   = blockIdx.x * 128;
    const int n0   = blockIdx.y * 128;
    const int wave = tid >> 6, lane = tid & 63;
    const int wm   = (wave >> 1) * 64;
    const int wn   = (wave & 1) * 64;
    const int lr   = lane & 15;
    const int lg   = lane >> 4;

    float4_t acc[4][4];
    #pragma unroll
    for (int m = 0; m < 4; ++m)
        #pragma unroll
        for (int n = 0; n < 4; ++n)
            acc[m][n] = (float4_t){0.f, 0.f, 0.f, 0.f};

    for (int k0 = 0; k0 < KDIM; k0 += 32) {
        #pragma unroll
        for (int it = 0; it < 2; ++it) {
            int slot = it * 256 + tid;
            int row = slot >> 2, cq = slot & 3;
            *reinterpret_cast<short8*>(&As[row * LDSP + cq * 8]) =
                *reinterpret_cast<const short8*>(
                    Xb + (size_t)(m0 + row) * KDIM + k0 + cq * 8);
        }
        #pragma unroll
        for (int it = 0; it < 2; ++it) {
            int slot = it * 256 + tid;
            int row = slot >> 2, cq = slot & 3;
            *reinterpret_cast<short8*>(&Bs[row * LDSP + cq * 8]) =
                *reinterpret_cast<const short8*>(
                    W + (size_t)(n0 + row) * KDIM + k0 + cq * 8);
        }
        __syncthreads();
        short8 af[4], bfr[4];
        #pragma unroll
        for (int m = 0; m < 4; ++m)
            af[m] = *reinterpret_cast<const short8*>(
                &As[(wm + m * 16 + lr) * LDSP + lg * 8]);
        #pragma unroll
        for (int n = 0; n < 4; ++n)
            bfr[n] = *reinterpret_cast<const short8*>(
                &Bs[(wn + n * 16 + lr) * LDSP + lg * 8]);
        #pragma unroll
        for (int m = 0; m < 4; ++m)
            #pragma unroll
            for (int n = 0; n < 4; ++n)
                acc[m][n] = __builtin_amdgcn_mfma_f32_16x16x32_bf16(
                    af[m], bfr[n], acc[m][n], 0, 0, 0);
        __syncthreads();
    }

    #pragma unroll
    for (int m = 0; m < 4; ++m) {
        #pragma unroll
        for (int n = 0; n < 4; ++n) {
            int gn = n0 + wn + n * 16 + lr;
            float bsv = bias[gn];
            #pragma unroll
            for (int r = 0; r < 4; ++r) {
                int gm = m0 + wm + m * 16 + lg * 4 + r;
                out[(size_t)gm * CCH + gn] = acc[m][n][r] + bsv;
            }
        }
    }
}

// ---------------------------------------------------------------- launch
extern "C" void kernel_launch(void* const* d_in, const int* in_sizes, int n_in,
                              void* d_out, int out_size, void* d_ws, size_t ws_size,
                              hipStream_t stream) {
    const float* x      = (const float*)d_in[0];
    const float* qkv_w  = (const float*)d_in[1];
    const float* qkv_b  = (const float*)d_in[2];
    const float* rpb    = (const float*)d_in[3];
    const float* proj_w = (const float*)d_in[4];
    const float* proj_b = (const float*)d_in[5];
    float* out = (float*)d_out;
    char* ws = (char*)d_ws;

    // ws layout (bytes):
    //   qkv bf16 (3*B*H*L*Dh = 25165824 elems)   @ 0          : 50331648
    //   ctx bf16 (16384*512  =  8388608 elems)   @ 50331648   : 16777216
    //   qkv_w bf16 (786432 elems)                @ 67108864   :  1572864
    //   proj_w bf16 (262144 elems)               @ 68681728   :   524288
    unsigned short* qkv = (unsigned short*)(ws);
    unsigned short* ctx = (unsigned short*)(ws + 50331648);
    unsigned short* wq  = (unsigned short*)(ws + 67108864);
    unsigned short* wp  = (unsigned short*)(ws + 68681728);

    cvt_f32_bf16_v4<<<768, 256, 0, stream>>>((const float4_t*)qkv_w, (short4_t*)wq, 786432 / 4);
    cvt_f32_bf16_v4<<<256, 256, 0, stream>>>((const float4_t*)proj_w, (short4_t*)wp, 262144 / 4);

    dim3 g1(M_TOT / 128, N_QKV / 128);   // 128 x 12
    gemm_qkv<<<g1, 256, 0, stream>>>(x, wq, qkv_b, qkv);

    natten_fwd<<<BATCH * HNUM * (LSEQ / 256), 256, 0, stream>>>(qkv, rpb, ctx);

    dim3 g2(M_TOT / 128, CCH / 128);     // 128 x 4
    gemm_proj<<<g2, 256, 0, stream>>>(ctx, wp, proj_b, out);
}

// Round 2
// 93.480 us; speedup vs baseline: 1.1074x; 1.1074x over previous
//
#include <hip/hip_runtime.h>
#include <hip/hip_bf16.h>

// Problem constants (B=4, L=4096, C=512, H=16, Dh=32, K=13)
#define BATCH   4
#define LSEQ    4096
#define CCH     512
#define HNUM    16
#define DH      32
#define KSZ     13
#define NHALF   6           // K/2
#define M_TOT   16384       // B*L
#define N_QKV   1536        // 3*C
#define KDIM    512         // C
#define BK      32          // GEMM K-step

typedef __attribute__((ext_vector_type(8))) short  short8;
typedef __attribute__((ext_vector_type(4))) short  short4_t;
typedef __attribute__((ext_vector_type(4))) float  float4_t;

__device__ __forceinline__ unsigned short f32_to_bf16(float f) {
    union { float f; unsigned int u; } un; un.f = f;
    unsigned int u = un.u;
    u += 0x7FFFu + ((u >> 16) & 1u);   // RNE (inputs are finite)
    return (unsigned short)(u >> 16);
}
__device__ __forceinline__ float bf16_to_f32(unsigned short h) {
    union { unsigned int u; float f; } un; un.u = ((unsigned int)h) << 16;
    return un.f;
}

// async global(16B/lane) -> LDS; lds base must be wave-uniform, HW adds lane*16
__device__ __forceinline__ void gload_lds16(const unsigned short* g, unsigned short* l) {
    __builtin_amdgcn_global_load_lds(
        (const __attribute__((address_space(1))) unsigned int*)g,
        (__attribute__((address_space(3))) unsigned int*)l,
        16, 0, 0);
}

// ---------------------------------------------------------------- cvt f32->bf16
__global__ void cvt_f32_bf16_v4(const float4_t* __restrict__ in,
                                short4_t* __restrict__ out, int n4) {
    int i = blockIdx.x * blockDim.x + threadIdx.x;
    int stride = gridDim.x * blockDim.x;
    for (; i < n4; i += stride) {
        float4_t v = in[i];
        short4_t h;
        h.x = (short)f32_to_bf16(v.x);
        h.y = (short)f32_to_bf16(v.y);
        h.z = (short)f32_to_bf16(v.z);
        h.w = (short)f32_to_bf16(v.w);
        out[i] = h;
    }
}

// ---------------------------------------------------------------- GEMM 1: QKV
// Xb (bf16, 16384x512) @ W^T (W bf16 1536x512) + bias -> qkv bf16 (3,B,H,L,Dh)
// m97 structure: 128x128 tile, BK=32, linear LDS, global_load_lds width=16.
__global__ __launch_bounds__(256) void gemm_qkv(
    const unsigned short* __restrict__ Xb,
    const unsigned short* __restrict__ W,
    const float* __restrict__ bias,
    unsigned short* __restrict__ qkvout)
{
    __shared__ __align__(16) unsigned short As[128 * BK];
    __shared__ __align__(16) unsigned short Bs[128 * BK];
    const int tid  = threadIdx.x;
    const int wv   = tid >> 6, ln = tid & 63;
    const int m0   = blockIdx.x * 128;
    const int n0   = blockIdx.y * 128;
    const int wm   = (wv >> 1) * 64;
    const int wn   = (wv & 1) * 64;
    const int lr   = ln & 15;          // fragment row/col
    const int lg   = ln >> 4;          // k-group (0..3)
    const int srow = ln >> 2;          // staging: row within 16-row chunk
    const int scol = (ln & 3) * 8;     // staging: element offset in row

    float4_t acc[4][4];
    #pragma unroll
    for (int m = 0; m < 4; ++m)
        #pragma unroll
        for (int n = 0; n < 4; ++n)
            acc[m][n] = (float4_t){0.f, 0.f, 0.f, 0.f};

    for (int k0 = 0; k0 < KDIM; k0 += BK) {
        // stage A+B tiles: 8 KB each, 2 wave-chunks of 1024B per wave
        #pragma unroll
        for (int it = 0; it < 2; ++it) {
            int chunk = it * 4 + wv;              // 0..7, wave-uniform
            int row   = chunk * 16 + srow;
            gload_lds16(Xb + (size_t)(m0 + row) * KDIM + k0 + scol,
                        &As[chunk * 16 * BK]);
            gload_lds16(W  + (size_t)(n0 + row) * KDIM + k0 + scol,
                        &Bs[chunk * 16 * BK]);
        }
        __syncthreads();
        short8 af[4], bfr[4];
        #pragma unroll
        for (int m = 0; m < 4; ++m)
            af[m] = *reinterpret_cast<const short8*>(
                &As[(wm + m * 16 + lr) * BK + lg * 8]);
        #pragma unroll
        for (int n = 0; n < 4; ++n)
            bfr[n] = *reinterpret_cast<const short8*>(
                &Bs[(wn + n * 16 + lr) * BK + lg * 8]);
        #pragma unroll
        for (int m = 0; m < 4; ++m)
            #pragma unroll
            for (int n = 0; n < 4; ++n)
                acc[m][n] = __builtin_amdgcn_mfma_f32_16x16x32_bf16(
                    af[m], bfr[n], acc[m][n], 0, 0, 0);
        __syncthreads();
    }

    // epilogue: bias, q-scale, scatter to (3,B,H,L,Dh) bf16
    const float qscale = 0.17677669529663687f;  // Dh^-0.5
    #pragma unroll
    for (int m = 0; m < 4; ++m) {
        #pragma unroll
        for (int n = 0; n < 4; ++n) {
            int gn    = n0 + wn + n * 16 + lr;
            int which = gn >> 9;            // 0=q 1=k 2=v
            int hh    = (gn >> 5) & 15;
            int dd    = gn & 31;
            float bsv = bias[gn];
            #pragma unroll
            for (int r = 0; r < 4; ++r) {
                int gm = m0 + wm + m * 16 + lg * 4 + r;
                float v = acc[m][n][r] + bsv;
                if (which == 0) v *= qscale;
                int b_ = gm >> 12, l = gm & 4095;
                size_t off = (((size_t)which * BATCH + b_) * HNUM + hh) *
                                 ((size_t)LSEQ * DH) + (size_t)l * DH + dd;
                qkvout[off] = f32_to_bf16(v);
            }
        }
    }
}

// ---------------------------------------------------------------- attention
// one block = (b, h, 256 consecutive l). K/V window staged in LDS.
__global__ __launch_bounds__(256) void natten_fwd(
    const unsigned short* __restrict__ qkv,  // (3,B,H,L,Dh) bf16
    const float* __restrict__ rpb,           // (16,25) f32
    unsigned short* __restrict__ ctx)        // (B,L,C) bf16
{
    __shared__ unsigned short ks[268 * DH];
    __shared__ unsigned short vs[268 * DH];
    __shared__ float rpb_s[2 * KSZ - 1];

    const int t    = threadIdx.x;
    const int lblk = blockIdx.x & 15;       // L/256 = 16 chunks
    const int bh   = blockIdx.x >> 4;
    const int hh   = bh & 15, b_ = bh >> 4;
    const int l0   = lblk * 256;

    const int r0    = max(l0 - NHALF, 0);
    const int rend  = min(l0 + 256 + NHALF, LSEQ);
    const int nrows = rend - r0;            // <= 268

    const size_t plane = (size_t)LSEQ * DH;
    const size_t kbase = (((size_t)1 * BATCH + b_) * HNUM + hh) * plane;
    const size_t vbase = (((size_t)2 * BATCH + b_) * HNUM + hh) * plane;

    for (int slot = t; slot < nrows * 4; slot += 256) {
        int row = slot >> 2, cq = slot & 3;
        *reinterpret_cast<short8*>(&ks[row * DH + cq * 8]) =
            *reinterpret_cast<const short8*>(&qkv[kbase + (size_t)(r0 + row) * DH + cq * 8]);
        *reinterpret_cast<short8*>(&vs[row * DH + cq * 8]) =
            *reinterpret_cast<const short8*>(&qkv[vbase + (size_t)(r0 + row) * DH + cq * 8]);
    }
    if (t < 2 * KSZ - 1) rpb_s[t] = rpb[hh * (2 * KSZ - 1) + t];
    __syncthreads();

    const int l = l0 + t;
    float q[DH];
    const size_t qoff = (((size_t)0 * BATCH + b_) * HNUM + hh) * plane + (size_t)l * DH;
    #pragma unroll
    for (int cq = 0; cq < 4; ++cq) {
        short8 qv = *reinterpret_cast<const short8*>(&qkv[qoff + cq * 8]);
        #pragma unroll
        for (int e = 0; e < 8; ++e) q[cq * 8 + e] = bf16_to_f32((unsigned short)qv[e]);
    }

    const int start = min(max(l - NHALF, 0), LSEQ - KSZ);
    float logit[KSZ];
    #pragma unroll
    for (int j = 0; j < KSZ; ++j) {
        int kr = start + j - r0;
        float s = 0.f;
        #pragma unroll
        for (int cq = 0; cq < 4; ++cq) {
            short8 kv = *reinterpret_cast<const short8*>(&ks[kr * DH + cq * 8]);
            #pragma unroll
            for (int e = 0; e < 8; ++e)
                s += q[cq * 8 + e] * bf16_to_f32((unsigned short)kv[e]);
        }
        logit[j] = s + rpb_s[start + j - l + (KSZ - 1)];
    }
    float mx = logit[0];
    #pragma unroll
    for (int j = 1; j < KSZ; ++j) mx = fmaxf(mx, logit[j]);
    float p[KSZ], sum = 0.f;
    #pragma unroll
    for (int j = 0; j < KSZ; ++j) { p[j] = __expf(logit[j] - mx); sum += p[j]; }
    const float inv = 1.f / sum;

    float o[DH];
    #pragma unroll
    for (int d = 0; d < DH; ++d) o[d] = 0.f;
    #pragma unroll
    for (int j = 0; j < KSZ; ++j) {
        int kr = start + j - r0;
        float pj = p[j] * inv;
        #pragma unroll
        for (int cq = 0; cq < 4; ++cq) {
            short8 vv = *reinterpret_cast<const short8*>(&vs[kr * DH + cq * 8]);
            #pragma unroll
            for (int e = 0; e < 8; ++e)
                o[cq * 8 + e] += pj * bf16_to_f32((unsigned short)vv[e]);
        }
    }
    const size_t obase = ((size_t)(b_ * LSEQ + l)) * CCH + hh * DH;
    #pragma unroll
    for (int cq = 0; cq < 4; ++cq) {
        short8 ov;
        #pragma unroll
        for (int e = 0; e < 8; ++e) ov[e] = (short)f32_to_bf16(o[cq * 8 + e]);
        *reinterpret_cast<short8*>(&ctx[obase + cq * 8]) = ov;
    }
}

// ---------------------------------------------------------------- GEMM 2: proj
// ctx (bf16, 16384x512) @ W^T (W bf16 512x512) + bias -> out f32 (B,L,C)
__global__ __launch_bounds__(256) void gemm_proj(
    const unsigned short* __restrict__ Xb,
    const unsigned short* __restrict__ W,
    const float* __restrict__ bias,
    float* __restrict__ out)
{
    __shared__ __align__(16) unsigned short As[128 * BK];
    __shared__ __align__(16) unsigned short Bs[128 * BK];
    const int tid  = threadIdx.x;
    const int wv   = tid >> 6, ln = tid & 63;
    const int m0   = blockIdx.x * 128;
    const int n0   = blockIdx.y * 128;
    const int wm   = (wv >> 1) * 64;
    const int wn   = (wv & 1) * 64;
    const int lr   = ln & 15;
    const int lg   = ln >> 4;
    const int srow = ln >> 2;
    const int scol = (ln & 3) * 8;

    float4_t acc[4][4];
    #pragma unroll
    for (int m = 0; m < 4; ++m)
        #pragma unroll
        for (int n = 0; n < 4; ++n)
            acc[m][n] = (float4_t){0.f, 0.f, 0.f, 0.f};

    for (int k0 = 0; k0 < KDIM; k0 += BK) {
        #pragma unroll
        for (int it = 0; it < 2; ++it) {
            int chunk = it * 4 + wv;
            int row   = chunk * 16 + srow;
            gload_lds16(Xb + (size_t)(m0 + row) * KDIM + k0 + scol,
                        &As[chunk * 16 * BK]);
            gload_lds16(W  + (size_t)(n0 + row) * KDIM + k0 + scol,
                        &Bs[chunk * 16 * BK]);
        }
        __syncthreads();
        short8 af[4], bfr[4];
        #pragma unroll
        for (int m = 0; m < 4; ++m)
            af[m] = *reinterpret_cast<const short8*>(
                &As[(wm + m * 16 + lr) * BK + lg * 8]);
        #pragma unroll
        for (int n = 0; n < 4; ++n)
            bfr[n] = *reinterpret_cast<const short8*>(
                &Bs[(wn + n * 16 + lr) * BK + lg * 8]);
        #pragma unroll
        for (int m = 0; m < 4; ++m)
            #pragma unroll
            for (int n = 0; n < 4; ++n)
                acc[m][n] = __builtin_amdgcn_mfma_f32_16x16x32_bf16(
                    af[m], bfr[n], acc[m][n], 0, 0, 0);
        __syncthreads();
    }

    #pragma unroll
    for (int m = 0; m < 4; ++m) {
        #pragma unroll
        for (int n = 0; n < 4; ++n) {
            int gn = n0 + wn + n * 16 + lr;
            float bsv = bias[gn];
            #pragma unroll
            for (int r = 0; r < 4; ++r) {
                int gm = m0 + wm + m * 16 + lg * 4 + r;
                out[(size_t)gm * CCH + gn] = acc[m][n][r] + bsv;
            }
        }
    }
}

// ---------------------------------------------------------------- launch
extern "C" void kernel_launch(void* const* d_in, const int* in_sizes, int n_in,
                              void* d_out, int out_size, void* d_ws, size_t ws_size,
                              hipStream_t stream) {
    const float* x      = (const float*)d_in[0];
    const float* qkv_w  = (const float*)d_in[1];
    const float* qkv_b  = (const float*)d_in[2];
    const float* rpb    = (const float*)d_in[3];
    const float* proj_w = (const float*)d_in[4];
    const float* proj_b = (const float*)d_in[5];
    float* out = (float*)d_out;
    char* ws = (char*)d_ws;

    // ws layout (bytes):
    //   qkv bf16 (3*B*H*L*Dh = 25165824 elems)   @ 0          : 50331648
    //   xb/ctx overlay (8388608 elems bf16)      @ 50331648   : 16777216
    //     xb  lifetime: cvt_x .. gemm_qkv   (disjoint from ctx)
    //     ctx lifetime: natten .. gemm_proj
    //   qkv_w bf16 (786432 elems)                @ 67108864   :  1572864
    //   proj_w bf16 (262144 elems)               @ 68681728   :   524288
    unsigned short* qkv = (unsigned short*)(ws);
    unsigned short* xb  = (unsigned short*)(ws + 50331648);
    unsigned short* ctx = (unsigned short*)(ws + 50331648);
    unsigned short* wq  = (unsigned short*)(ws + 67108864);
    unsigned short* wp  = (unsigned short*)(ws + 68681728);

    // f32 -> bf16 conversions (x reused 12x by N-tiles; convert once)
    cvt_f32_bf16_v4<<<2048, 256, 0, stream>>>((const float4_t*)x, (short4_t*)xb, M_TOT * KDIM / 4);
    cvt_f32_bf16_v4<<<768, 256, 0, stream>>>((const float4_t*)qkv_w, (short4_t*)wq, 786432 / 4);
    cvt_f32_bf16_v4<<<256, 256, 0, stream>>>((const float4_t*)proj_w, (short4_t*)wp, 262144 / 4);

    dim3 g1(M_TOT / 128, N_QKV / 128);   // 128 x 12
    gemm_qkv<<<g1, 256, 0, stream>>>(xb, wq, qkv_b, qkv);

    natten_fwd<<<BATCH * HNUM * (LSEQ / 256), 256, 0, stream>>>(qkv, rpb, ctx);

    dim3 g2(M_TOT / 128, CCH / 128);     // 128 x 4
    gemm_proj<<<g2, 256, 0, stream>>>(ctx, wp, proj_b, out);
}

// Round 3
// 88.167 us; speedup vs baseline: 1.1741x; 1.0603x over previous
//
#include <hip/hip_runtime.h>
#include <hip/hip_bf16.h>

// Problem constants (B=4, L=4096, C=512, H=16, Dh=32, K=13)
#define BATCH   4
#define LSEQ    4096
#define CCH     512
#define HNUM    16
#define DH      32
#define KSZ     13
#define NHALF   6           // K/2
#define M_TOT   16384       // B*L
#define N_QKV   1536        // 3*C
#define KDIM    512         // C
#define BK      64          // GEMM K-step (128B rows -> XOR-swizzle domain of 8 chunks)

typedef __attribute__((ext_vector_type(8))) short  short8;
typedef __attribute__((ext_vector_type(4))) short  short4_t;
typedef __attribute__((ext_vector_type(4))) float  float4_t;

__device__ __forceinline__ unsigned short f32_to_bf16(float f) {
    union { float f; unsigned int u; } un; un.f = f;
    unsigned int u = un.u;
    u += 0x7FFFu + ((u >> 16) & 1u);   // RNE (inputs are finite)
    return (unsigned short)(u >> 16);
}
__device__ __forceinline__ float bf16_to_f32(unsigned short h) {
    union { unsigned int u; float f; } un; un.u = ((unsigned int)h) << 16;
    return un.f;
}

// async global(16B/lane) -> LDS; lds base must be wave-uniform, HW adds lane*16
__device__ __forceinline__ void gload_lds16(const unsigned short* g, unsigned short* l) {
    __builtin_amdgcn_global_load_lds(
        (const __attribute__((address_space(1))) unsigned int*)g,
        (__attribute__((address_space(3))) unsigned int*)l,
        16, 0, 0);
}

// ---------------------------------------------------------------- cvt f32->bf16
__global__ void cvt_f32_bf16_v4(const float4_t* __restrict__ in,
                                short4_t* __restrict__ out, int n4) {
    int i = blockIdx.x * blockDim.x + threadIdx.x;
    int stride = gridDim.x * blockDim.x;
    for (; i < n4; i += stride) {
        float4_t v = in[i];
        short4_t h;
        h.x = (short)f32_to_bf16(v.x);
        h.y = (short)f32_to_bf16(v.y);
        h.z = (short)f32_to_bf16(v.z);
        h.w = (short)f32_to_bf16(v.w);
        out[i] = h;
    }
}

// ---------------------------------------------------------------- GEMM 1: QKV
// Xb (bf16, 16384x512) @ W^T (W bf16 1536x512) + bias -> qkv bf16 (3,B,H,L,Dh)
// 128x128 tile, BK=64, global_load_lds w=16 with source-side XOR swizzle:
//   LDS position (row, c) holds global chunk c ^ (row&7); ds_read applies the
//   same involution -> every 16-lane fragment read spreads over 8 chunk slots
//   (2-way max bank aliasing = free).
__global__ __launch_bounds__(256) void gemm_qkv(
    const unsigned short* __restrict__ Xb,
    const unsigned short* __restrict__ W,
    const float* __restrict__ bias,
    unsigned short* __restrict__ qkvout)
{
    __shared__ __align__(16) unsigned short As[128 * BK];
    __shared__ __align__(16) unsigned short Bs[128 * BK];
    const int tid  = threadIdx.x;
    const int wv   = tid >> 6, ln = tid & 63;
    const int m0   = blockIdx.x * 128;
    const int n0   = blockIdx.y * 128;
    const int wm   = (wv >> 1) * 64;
    const int wn   = (wv & 1) * 64;
    const int lr   = ln & 15;          // fragment row/col
    const int lg   = ln >> 4;          // k-group (0..3)
    const int rgrp = ln >> 3;          // staging: row within 8-row chunk (0..7)
    const int csw  = ((ln & 7) ^ rgrp) * 8;  // staging: swizzled source chunk (elems)

    float4_t acc[4][4];
    #pragma unroll
    for (int m = 0; m < 4; ++m)
        #pragma unroll
        for (int n = 0; n < 4; ++n)
            acc[m][n] = (float4_t){0.f, 0.f, 0.f, 0.f};

    for (int k0 = 0; k0 < KDIM; k0 += BK) {
        // stage A+B tiles (16 KB each): 16 chunks of 8 rows x 128B, 4 per wave
        #pragma unroll
        for (int it = 0; it < 4; ++it) {
            int ch  = it * 4 + wv;               // 0..15, wave-uniform
            int row = ch * 8 + rgrp;
            gload_lds16(Xb + (size_t)(m0 + row) * KDIM + k0 + csw,
                        &As[ch * 8 * BK]);
            gload_lds16(W  + (size_t)(n0 + row) * KDIM + k0 + csw,
                        &Bs[ch * 8 * BK]);
        }
        __syncthreads();
        short8 af[2][4], bfr[2][4];
        #pragma unroll
        for (int kk = 0; kk < 2; ++kk) {
            #pragma unroll
            for (int m = 0; m < 4; ++m) {
                int row = wm + m * 16 + lr;
                int c   = (kk * 4 + lg) ^ (row & 7);
                af[kk][m] = *reinterpret_cast<const short8*>(&As[row * BK + c * 8]);
            }
            #pragma unroll
            for (int n = 0; n < 4; ++n) {
                int row = wn + n * 16 + lr;
                int c   = (kk * 4 + lg) ^ (row & 7);
                bfr[kk][n] = *reinterpret_cast<const short8*>(&Bs[row * BK + c * 8]);
            }
        }
        #pragma unroll
        for (int kk = 0; kk < 2; ++kk)
            #pragma unroll
            for (int m = 0; m < 4; ++m)
                #pragma unroll
                for (int n = 0; n < 4; ++n)
                    acc[m][n] = __builtin_amdgcn_mfma_f32_16x16x32_bf16(
                        af[kk][m], bfr[kk][n], acc[m][n], 0, 0, 0);
        __syncthreads();
    }

    // epilogue: bias, q-scale, scatter to (3,B,H,L,Dh) bf16
    const float qscale = 0.17677669529663687f;  // Dh^-0.5
    #pragma unroll
    for (int m = 0; m < 4; ++m) {
        #pragma unroll
        for (int n = 0; n < 4; ++n) {
            int gn    = n0 + wn + n * 16 + lr;
            int which = gn >> 9;            // 0=q 1=k 2=v
            int hh    = (gn >> 5) & 15;
            int dd    = gn & 31;
            float bsv = bias[gn];
            #pragma unroll
            for (int r = 0; r < 4; ++r) {
                int gm = m0 + wm + m * 16 + lg * 4 + r;
                float v = acc[m][n][r] + bsv;
                if (which == 0) v *= qscale;
                int b_ = gm >> 12, l = gm & 4095;
                size_t off = (((size_t)which * BATCH + b_) * HNUM + hh) *
                                 ((size_t)LSEQ * DH) + (size_t)l * DH + dd;
                qkvout[off] = f32_to_bf16(v);
            }
        }
    }
}

// ---------------------------------------------------------------- attention
// one block = (b, h, 256 consecutive l). K/V window staged in LDS.
__global__ __launch_bounds__(256) void natten_fwd(
    const unsigned short* __restrict__ qkv,  // (3,B,H,L,Dh) bf16
    const float* __restrict__ rpb,           // (16,25) f32
    unsigned short* __restrict__ ctx)        // (B,L,C) bf16
{
    __shared__ unsigned short ks[268 * DH];
    __shared__ unsigned short vs[268 * DH];
    __shared__ float rpb_s[2 * KSZ - 1];

    const int t    = threadIdx.x;
    const int lblk = blockIdx.x & 15;       // L/256 = 16 chunks
    const int bh   = blockIdx.x >> 4;
    const int hh   = bh & 15, b_ = bh >> 4;
    const int l0   = lblk * 256;

    const int r0    = max(l0 - NHALF, 0);
    const int rend  = min(l0 + 256 + NHALF, LSEQ);
    const int nrows = rend - r0;            // <= 268

    const size_t plane = (size_t)LSEQ * DH;
    const size_t kbase = (((size_t)1 * BATCH + b_) * HNUM + hh) * plane;
    const size_t vbase = (((size_t)2 * BATCH + b_) * HNUM + hh) * plane;

    for (int slot = t; slot < nrows * 4; slot += 256) {
        int row = slot >> 2, cq = slot & 3;
        *reinterpret_cast<short8*>(&ks[row * DH + cq * 8]) =
            *reinterpret_cast<const short8*>(&qkv[kbase + (size_t)(r0 + row) * DH + cq * 8]);
        *reinterpret_cast<short8*>(&vs[row * DH + cq * 8]) =
            *reinterpret_cast<const short8*>(&qkv[vbase + (size_t)(r0 + row) * DH + cq * 8]);
    }
    if (t < 2 * KSZ - 1) rpb_s[t] = rpb[hh * (2 * KSZ - 1) + t];
    __syncthreads();

    const int l = l0 + t;
    float q[DH];
    const size_t qoff = (((size_t)0 * BATCH + b_) * HNUM + hh) * plane + (size_t)l * DH;
    #pragma unroll
    for (int cq = 0; cq < 4; ++cq) {
        short8 qv = *reinterpret_cast<const short8*>(&qkv[qoff + cq * 8]);
        #pragma unroll
        for (int e = 0; e < 8; ++e) q[cq * 8 + e] = bf16_to_f32((unsigned short)qv[e]);
    }

    const int start = min(max(l - NHALF, 0), LSEQ - KSZ);
    float logit[KSZ];
    #pragma unroll
    for (int j = 0; j < KSZ; ++j) {
        int kr = start + j - r0;
        float s = 0.f;
        #pragma unroll
        for (int cq = 0; cq < 4; ++cq) {
            short8 kv = *reinterpret_cast<const short8*>(&ks[kr * DH + cq * 8]);
            #pragma unroll
            for (int e = 0; e < 8; ++e)
                s += q[cq * 8 + e] * bf16_to_f32((unsigned short)kv[e]);
        }
        logit[j] = s + rpb_s[start + j - l + (KSZ - 1)];
    }
    float mx = logit[0];
    #pragma unroll
    for (int j = 1; j < KSZ; ++j) mx = fmaxf(mx, logit[j]);
    float p[KSZ], sum = 0.f;
    #pragma unroll
    for (int j = 0; j < KSZ; ++j) { p[j] = __expf(logit[j] - mx); sum += p[j]; }
    const float inv = 1.f / sum;

    float o[DH];
    #pragma unroll
    for (int d = 0; d < DH; ++d) o[d] = 0.f;
    #pragma unroll
    for (int j = 0; j < KSZ; ++j) {
        int kr = start + j - r0;
        float pj = p[j] * inv;
        #pragma unroll
        for (int cq = 0; cq < 4; ++cq) {
            short8 vv = *reinterpret_cast<const short8*>(&vs[kr * DH + cq * 8]);
            #pragma unroll
            for (int e = 0; e < 8; ++e)
                o[cq * 8 + e] += pj * bf16_to_f32((unsigned short)vv[e]);
        }
    }
    const size_t obase = ((size_t)(b_ * LSEQ + l)) * CCH + hh * DH;
    #pragma unroll
    for (int cq = 0; cq < 4; ++cq) {
        short8 ov;
        #pragma unroll
        for (int e = 0; e < 8; ++e) ov[e] = (short)f32_to_bf16(o[cq * 8 + e]);
        *reinterpret_cast<short8*>(&ctx[obase + cq * 8]) = ov;
    }
}

// ---------------------------------------------------------------- GEMM 2: proj
// ctx (bf16, 16384x512) @ W^T (W bf16 512x512) + bias -> out f32 (B,L,C)
__global__ __launch_bounds__(256) void gemm_proj(
    const unsigned short* __restrict__ Xb,
    const unsigned short* __restrict__ W,
    const float* __restrict__ bias,
    float* __restrict__ out)
{
    __shared__ __align__(16) unsigned short As[128 * BK];
    __shared__ __align__(16) unsigned short Bs[128 * BK];
    const int tid  = threadIdx.x;
    const int wv   = tid >> 6, ln = tid & 63;
    const int m0   = blockIdx.x * 128;
    const int n0   = blockIdx.y * 128;
    const int wm   = (wv >> 1) * 64;
    const int wn   = (wv & 1) * 64;
    const int lr   = ln & 15;
    const int lg   = ln >> 4;
    const int rgrp = ln >> 3;
    const int csw  = ((ln & 7) ^ rgrp) * 8;

    float4_t acc[4][4];
    #pragma unroll
    for (int m = 0; m < 4; ++m)
        #pragma unroll
        for (int n = 0; n < 4; ++n)
            acc[m][n] = (float4_t){0.f, 0.f, 0.f, 0.f};

    for (int k0 = 0; k0 < KDIM; k0 += BK) {
        #pragma unroll
        for (int it = 0; it < 4; ++it) {
            int ch  = it * 4 + wv;
            int row = ch * 8 + rgrp;
            gload_lds16(Xb + (size_t)(m0 + row) * KDIM + k0 + csw,
                        &As[ch * 8 * BK]);
            gload_lds16(W  + (size_t)(n0 + row) * KDIM + k0 + csw,
                        &Bs[ch * 8 * BK]);
        }
        __syncthreads();
        short8 af[2][4], bfr[2][4];
        #pragma unroll
        for (int kk = 0; kk < 2; ++kk) {
            #pragma unroll
            for (int m = 0; m < 4; ++m) {
                int row = wm + m * 16 + lr;
                int c   = (kk * 4 + lg) ^ (row & 7);
                af[kk][m] = *reinterpret_cast<const short8*>(&As[row * BK + c * 8]);
            }
            #pragma unroll
            for (int n = 0; n < 4; ++n) {
                int row = wn + n * 16 + lr;
                int c   = (kk * 4 + lg) ^ (row & 7);
                bfr[kk][n] = *reinterpret_cast<const short8*>(&Bs[row * BK + c * 8]);
            }
        }
        #pragma unroll
        for (int kk = 0; kk < 2; ++kk)
            #pragma unroll
            for (int m = 0; m < 4; ++m)
                #pragma unroll
                for (int n = 0; n < 4; ++n)
                    acc[m][n] = __builtin_amdgcn_mfma_f32_16x16x32_bf16(
                        af[kk][m], bfr[kk][n], acc[m][n], 0, 0, 0);
        __syncthreads();
    }

    #pragma unroll
    for (int m = 0; m < 4; ++m) {
        #pragma unroll
        for (int n = 0; n < 4; ++n) {
            int gn = n0 + wn + n * 16 + lr;
            float bsv = bias[gn];
            #pragma unroll
            for (int r = 0; r < 4; ++r) {
                int gm = m0 + wm + m * 16 + lg * 4 + r;
                out[(size_t)gm * CCH + gn] = acc[m][n][r] + bsv;
            }
        }
    }
}

// ---------------------------------------------------------------- launch
extern "C" void kernel_launch(void* const* d_in, const int* in_sizes, int n_in,
                              void* d_out, int out_size, void* d_ws, size_t ws_size,
                              hipStream_t stream) {
    const float* x      = (const float*)d_in[0];
    const float* qkv_w  = (const float*)d_in[1];
    const float* qkv_b  = (const float*)d_in[2];
    const float* rpb    = (const float*)d_in[3];
    const float* proj_w = (const float*)d_in[4];
    const float* proj_b = (const float*)d_in[5];
    float* out = (float*)d_out;
    char* ws = (char*)d_ws;

    // ws layout (bytes):
    //   qkv bf16 (3*B*H*L*Dh = 25165824 elems)   @ 0          : 50331648
    //   xb/ctx overlay (8388608 elems bf16)      @ 50331648   : 16777216
    //     xb  lifetime: cvt_x .. gemm_qkv   (disjoint from ctx)
    //     ctx lifetime: natten .. gemm_proj
    //   qkv_w bf16 (786432 elems)                @ 67108864   :  1572864
    //   proj_w bf16 (262144 elems)               @ 68681728   :   524288
    unsigned short* qkv = (unsigned short*)(ws);
    unsigned short* xb  = (unsigned short*)(ws + 50331648);
    unsigned short* ctx = (unsigned short*)(ws + 50331648);
    unsigned short* wq  = (unsigned short*)(ws + 67108864);
    unsigned short* wp  = (unsigned short*)(ws + 68681728);

    // f32 -> bf16 conversions (x reused 12x by N-tiles; convert once)
    cvt_f32_bf16_v4<<<2048, 256, 0, stream>>>((const float4_t*)x, (short4_t*)xb, M_TOT * KDIM / 4);
    cvt_f32_bf16_v4<<<768, 256, 0, stream>>>((const float4_t*)qkv_w, (short4_t*)wq, 786432 / 4);
    cvt_f32_bf16_v4<<<256, 256, 0, stream>>>((const float4_t*)proj_w, (short4_t*)wp, 262144 / 4);

    dim3 g1(M_TOT / 128, N_QKV / 128);   // 128 x 12
    gemm_qkv<<<g1, 256, 0, stream>>>(xb, wq, qkv_b, qkv);

    natten_fwd<<<BATCH * HNUM * (LSEQ / 256), 256, 0, stream>>>(qkv, rpb, ctx);

    dim3 g2(M_TOT / 128, CCH / 128);     // 128 x 4
    gemm_proj<<<g2, 256, 0, stream>>>(ctx, wp, proj_b, out);
}